// Round 16
// baseline (1284.656 us; speedup 1.0000x reference)
//
#include <hip/hip_runtime.h>

typedef short short8 __attribute__((ext_vector_type(8)));
typedef float f32x4 __attribute__((ext_vector_type(4)));
typedef unsigned short u16;
typedef unsigned int u32;

#define C64 64
#define HWp (512*512)
#define NWG 256    // 4 images x 64 bands of 8 owned rows; 1 block/CU
#define PR 72      // LDS row stride in u16 (144 B)
#define SLOTS 18   // state window absrows a-5 .. a+12 (slot = m+1)
#define SBUF 2048  // u16 per state plane buffer
#define UBUF 2048  // u16 per u plane buffer
#define NEP 128    // 511 = 4*127 + 3

struct Ws {
  int flags[NWG][32];        // one 128B line per band
  u32 haloT[NWG][2][4*64];   // owned rows absr a..a+3   (m=4..7)
  u32 haloB[NWG][2][4*64];   // owned rows absr a+4..a+7 (m=8..11)
};

__device__ __forceinline__ u16 f2bf(float f){
  u32 r;
  asm("v_cvt_pk_bf16_f32 %0, %1, %1" : "=v"(r) : "v"(f));  // RNE, 1 instr
  return (u16)r;
}
__device__ __forceinline__ float bf2f(u16 h){ return __uint_as_float(((u32)h) << 16); }
__device__ __forceinline__ f32x4 splat4(float x){ f32x4 v = {x,x,x,x}; return v; }
__device__ __forceinline__ float sigm(float x){ return 1.f/(1.f + __expf(-x)); }
__device__ __forceinline__ float tanh_(float x){ float e = __expf(2.f*x); return 1.f - 2.f/(e + 1.f); }

#define MFMA16(a,b,c) __builtin_amdgcn_mfma_f32_16x16x32_bf16(a,b,c,0,0,0)
#define ATOM_ST(p,v) __hip_atomic_store((p),(v),__ATOMIC_RELAXED,__HIP_MEMORY_SCOPE_AGENT)
#define ATOM_LD(p)   __hip_atomic_load((p),__ATOMIC_RELAXED,__HIP_MEMORY_SCOPE_AGENT)
// merged 3-term hi/lo product (r5/r11-verified numerics)
#define DOT3(acc, XH, XL, WH, WL) \
  acc = MFMA16(XH, WH, acc); acc = MFMA16(XL, WH, acc); acc = MFMA16(XH, WL, acc);

__global__ void reset_flags(int* flags) {
  if (threadIdx.x < NWG) flags[threadIdx.x * 32] = -1;
}

// ---- per-step building blocks; S selects the independent accumulator half ----
#define AKK(S, kk) {                                                     \
  const int _o = PS + aoff + ((kk)>>1)*PR + ((kk)&1)*32;                 \
  short8 Ah = *(const short8*)&sh[_o];                                   \
  short8 Al = *(const short8*)&sl[_o];                                   \
  DOT3(aR##S, Ah, Al, BihH[0][kk], BihL[0][kk]);                         \
  DOT3(aZ##S, Ah, Al, BihH[1][kk], BihL[1][kk]);                         \
  DOT3(aI##S, Ah, Al, BihH[2][kk], BihL[2][kk]); }

#define XKT(S, kt) {                                                     \
  const int _o = PU + aoff + (kt)*32;                                    \
  short8 Xh = *(const short8*)&uh[_o];                                   \
  short8 Xl = *(const short8*)&ul[_o];                                   \
  DOT3(aR##S, Xh, Xl, BhhH[0][kt], BhhL[0][kt]);                         \
  DOT3(aZ##S, Xh, Xl, BhhH[1][kt], BhhL[1][kt]);                         \
  DOT3(aH##S, Xh, Xl, BhhH[2][kt], BhhL[2][kt]); }

#define GWB(j) {                                                         \
  const int m = kgrp*4 + (j);                                            \
  const int absr = a - 4 + m;                                            \
  float r = sigm(aR0[j] + aR1[j]);                                       \
  float z = sigm(aZ0[j] + aZ1[j]);                                       \
  float nn = tanh_(aI0[j] + aI1[j] + r*(aH0[j] + aH1[j]));               \
  float cur = bf2f(uh[PU + m*PR + ch]) + bf2f(ul[PU + m*PR + ch]);       \
  float v = (1.f - z)*nn + z*cur;                                        \
  if ((unsigned)absr < 512u) {                                           \
    u16 h_ = f2bf(v);                                                    \
    sh[PN + (m+1)*PR + ch] = h_;                                         \
    sl[PN + (m+1)*PR + ch] = f2bf(v - bf2f(h_));                         \
  }                                                                      \
  if (m >= 4 && m < 12)                                                  \
    ost[(dc0 + DD)*512 + (m-4)*64 + ch] = f2bf(v);                       \
  if (DD == 3) {                                                         \
    if (kgrp == 1) ATOM_ST(&ws->haloT[g][e&1][(j)*64 + ch], __float_as_uint(v)); \
    if (kgrp == 2) ATOM_ST(&ws->haloB[g][e&1][(j)*64 + ch], __float_as_uint(v)); \
  } }

#define UST(i) {                                                         \
  float v = nv[i];                                                       \
  u16 h_ = f2bf(v);                                                      \
  uh[PV + uoff[i]] = h_;                                                 \
  ul[PV + uoff[i]] = f2bf(v - bf2f(h_)); }

#define STEP(DD_) {                                                      \
  enum { DD = DD_, PS = (DD&1)*SBUF, PN = ((DD&1)^1)*SBUF,               \
         PU = (DD&1)*UBUF, PV = ((DD&1)^1)*UBUF };                       \
  float nv[4];                                                           \
  { int cc = 4*e + 2 + DD; if (cc > 511) cc = 511;                       \
    nv[0] = frow0[cc]; nv[1] = frow1[cc];                                \
    nv[2] = frow2[cc]; nv[3] = frow3[cc]; }                              \
  f32x4 aR0 = splat4(biasR), aZ0 = splat4(biasZ);                        \
  f32x4 aI0 = splat4(biasI), aH0 = splat4(biasHn);                       \
  f32x4 aR1 = splat4(0.f), aZ1 = splat4(0.f);                            \
  f32x4 aI1 = splat4(0.f), aH1 = splat4(0.f);                            \
  AKK(0,0) AKK(1,3) AKK(0,1) AKK(1,4) AKK(0,2) AKK(1,5)                  \
  XKT(0,0) XKT(1,1)                                                      \
  GWB(0) GWB(1) GWB(2) GWB(3)                                            \
  UST(0) UST(1) UST(2) UST(3)                                            \
}

__global__ __launch_bounds__(256, 1)
void gru_scan(const float* __restrict__ feat,
              const float* __restrict__ w_ih,
              const float* __restrict__ w_hh,
              const float* __restrict__ b_ih,
              const float* __restrict__ b_hh,
              float* __restrict__ out,
              Ws* __restrict__ ws)
{
  __shared__ __align__(16) u16 sh[2*SBUF], sl[2*SBUF];
  __shared__ __align__(16) u16 uh[2*UBUF], ul[2*UBUF];
  __shared__ __align__(16) u16 ost[16*512];   // [dc][row0..7][ch] bf16, conflict-free writes

  const int tid  = threadIdx.x;
  const int wgid = blockIdx.x;
  const int g    = (wgid & 7) * 32 + (wgid >> 3);   // XCD-local band chains (bijective)
  const int b    = g >> 6;
  const int kband= g & 63;
  const int a    = kband * 8;
  const int lane = tid & 63;
  const int wid  = tid >> 6;
  const int ln16 = lane & 15;
  const int kgrp = lane >> 4;
  const int ch   = wid*16 + ln16;

  // ---- weights (hi+lo) in registers: 192 VGPR ----
  short8 BihH[3][6], BihL[3][6], BhhH[3][2], BhhL[3][2];
#pragma unroll
  for (int gg = 0; gg < 3; ++gg) {
    const int n = gg*64 + ch;
#pragma unroll
    for (int kk = 0; kk < 6; ++kk) {
      short8 vh, vl;
#pragma unroll
      for (int j = 0; j < 8; ++j) {
        float wv = w_ih[n*192 + kk*32 + kgrp*8 + j];
        u16 h = f2bf(wv); vh[j] = (short)h; vl[j] = (short)f2bf(wv - bf2f(h));
      }
      BihH[gg][kk] = vh; BihL[gg][kk] = vl;
    }
#pragma unroll
    for (int kt = 0; kt < 2; ++kt) {
      short8 vh, vl;
#pragma unroll
      for (int j = 0; j < 8; ++j) {
        float wv = w_hh[n*64 + kt*32 + kgrp*8 + j];
        u16 h = f2bf(wv); vh[j] = (short)h; vl[j] = (short)f2bf(wv - bf2f(h));
      }
      BhhH[gg][kt] = vh; BhhL[gg][kt] = vl;
    }
  }
  const float biasR  = b_ih[ch]       + b_hh[ch];
  const float biasZ  = b_ih[64 + ch]  + b_hh[64 + ch];
  const float biasI  = b_ih[128 + ch];
  const float biasHn = b_hh[128 + ch];

  // ---- static per-thread offsets ----
  const int aoff = ln16*PR + kgrp*8;
  const int lch  = tid & 63;
  const int lr0  = wid * 4;                 // loader u-rows m=lr0..lr0+3
  int uoff[4];
#pragma unroll
  for (int i = 0; i < 4; ++i) uoff[i] = (lr0 + i)*PR + lch;

  const float* fbase = feat + (size_t)(b*C64 + lch)*HWp;
  // clamped row pointers (no masks: garbage flows only into discarded margin rows)
  const int ar0 = a - 4 + lr0;
  int r0 = ar0+0; r0 = r0 < 0 ? 0 : (r0 > 511 ? 511 : r0);
  int r1 = ar0+1; r1 = r1 < 0 ? 0 : (r1 > 511 ? 511 : r1);
  int r2 = ar0+2; r2 = r2 < 0 ? 0 : (r2 > 511 ? 511 : r2);
  int r3 = ar0+3; r3 = r3 < 0 ? 0 : (r3 > 511 ? 511 : r3);
  const float* frow0 = fbase + (size_t)r0*512;
  const float* frow1 = fbase + (size_t)r1*512;
  const float* frow2 = fbase + (size_t)r2*512;
  const float* frow3 = fbase + (size_t)r3*512;

  // ---- init ----
  for (int i = tid; i < 2*SBUF; i += 256) { sh[i] = 0; sl[i] = 0; }
  for (int i = tid; i < 2*UBUF; i += 256) { uh[i] = 0; ul[i] = 0; }
  __syncthreads();
  // feat col 0 -> state buf0 slots 0..17 + owned passthrough (slots 5..12)
#pragma unroll
  for (int i = 0; i < 5; ++i) {
    const int s = wid + 4*i;
    if (s < SLOTS) {
      const int absr = a - 5 + s;
      if ((unsigned)absr < 512u) {
        float v = fbase[(size_t)absr*512];
        u16 h_ = f2bf(v);
        sh[s*PR + lch] = h_;
        sl[s*PR + lch] = f2bf(v - bf2f(h_));
        if (s >= 5 && s <= 12) out[(size_t)(b*C64 + lch)*HWp + (size_t)absr*512] = v;
      }
    }
  }
  // u buf0 <- col 1 (clamped rows)
  {
    const float* fr[4] = { frow0, frow1, frow2, frow3 };
#pragma unroll
    for (int i = 0; i < 4; ++i) {
      float v1 = fr[i][1];
      u16 h_ = f2bf(v1);
      uh[uoff[i]] = h_;
      ul[uoff[i]] = f2bf(v1 - bf2f(h_));
    }
  }
  __syncthreads();

  // ---- epoch loop: 4 columns per epoch, static parity ----
#pragma unroll 1
  for (int e = 0; e < NEP; ++e) {
    const int dc0 = (e & 3) * 4;
    STEP(0)
    __syncthreads();
    STEP(1)
    __syncthreads();
    STEP(2)
    if (e < NEP-1) {
      __syncthreads();
      STEP(3)
    }

    // ---- boundary ----
    asm volatile("s_waitcnt vmcnt(0)" ::: "memory");   // per-wave drain (halo sends)
    __syncthreads();
    if (e < NEP-1 && tid == 0) ATOM_ST(&ws->flags[g][0], e);

    if (wid == 0 || wid == 3) {
      if ((e & 3) == 3) {      // flush 16 finished columns; 64B/lane-row, coalesced
        const int t128  = (wid == 0) ? lane : 64 + lane;
        const int wbase = 4*(e-3) + 1;
#pragma unroll
        for (int i = 0; i < 4; ++i) {
          const int pi  = t128 + 128*i;      // row*64 + ch
          const int row = pi >> 6, c = pi & 63;
          float* go = out + (size_t)(b*C64 + c)*HWp + (size_t)(a + row)*512 + wbase;
#pragma unroll
          for (int dc = 0; dc < 16; ++dc)
            if (wbase + dc <= 511) go[dc] = bf2f(ost[dc*512 + row*64 + c]);
        }
      }
    } else if (e < NEP-1) {
      if (wid == 1 && kband > 0) {       // top margin <- g-1's haloB (absr a-4..a-1)
        int f = -1, guard = 0;
        while (f < e && ++guard < (1<<17)) {
          if (lane == 0) f = ATOM_LD(&ws->flags[g-1][0]);
          f = __shfl(f, 0);
          if (f < e) __builtin_amdgcn_s_sleep(1);
        }
        asm volatile("" ::: "memory");
#pragma unroll
        for (int i = 0; i < 4; ++i) {    // absr a-4+i -> buf0 slot 1+i
          float v = __uint_as_float(ATOM_LD(&ws->haloB[g-1][e&1][i*64 + lane]));
          u16 h_ = f2bf(v);
          sh[(1+i)*PR + lane] = h_;
          sl[(1+i)*PR + lane] = f2bf(v - bf2f(h_));
        }
      }
      if (wid == 2 && kband < 63) {      // bottom margin <- g+1's haloT (absr a+8..a+11)
        int f = -1, guard = 0;
        while (f < e && ++guard < (1<<17)) {
          if (lane == 0) f = ATOM_LD(&ws->flags[g+1][0]);
          f = __shfl(f, 0);
          if (f < e) __builtin_amdgcn_s_sleep(1);
        }
        asm volatile("" ::: "memory");
#pragma unroll
        for (int i = 0; i < 4; ++i) {    // absr a+8+i -> buf0 slot 13+i
          float v = __uint_as_float(ATOM_LD(&ws->haloT[g+1][e&1][i*64 + lane]));
          u16 h_ = f2bf(v);
          sh[(13+i)*PR + lane] = h_;
          sl[(13+i)*PR + lane] = f2bf(v - bf2f(h_));
        }
      }
    }
    __syncthreads();   // margins in buf0 + flush done before next epoch
  }
}

extern "C" void kernel_launch(void* const* d_in, const int* in_sizes, int n_in,
                              void* d_out, int out_size, void* d_ws, size_t ws_size,
                              hipStream_t stream) {
  const float* feat = (const float*)d_in[0];
  const float* wih  = (const float*)d_in[1];
  const float* whh  = (const float*)d_in[2];
  const float* bih  = (const float*)d_in[3];
  const float* bhh  = (const float*)d_in[4];
  float* out = (float*)d_out;
  Ws* ws = (Ws*)d_ws;

  reset_flags<<<1, NWG, 0, stream>>>((int*)ws->flags);
  gru_scan<<<NWG, 256, 0, stream>>>(feat, wih, whh, bih, bhh, out, ws);
}

// Round 17
// 1195.241 us; speedup vs baseline: 1.0748x; 1.0748x over previous
//
#include <hip/hip_runtime.h>

typedef short short8 __attribute__((ext_vector_type(8)));
typedef float f32x4 __attribute__((ext_vector_type(4)));
typedef unsigned short u16;
typedef unsigned int u32;

#define C64 64
#define HWp (512*512)
#define NWG 256    // 4 images x 64 bands of 8 owned rows; 1 block/CU
#define PR 72      // LDS row stride in u16 (144 B)
#define SLOTS 18   // state window absrows a-5 .. a+12 (slot = m+1)
#define SBUF 2048  // u16 per state plane buffer
#define UBUF 2048  // u16 per u plane buffer
#define NEP 128    // 511 = 4*127 + 3

struct Ws {
  int flags[NWG][32];        // one 128B line per band
  u32 haloT[NWG][2][4*64];   // owned rows absr a..a+3   (m=4..7)
  u32 haloB[NWG][2][4*64];   // owned rows absr a+4..a+7 (m=8..11)
};

__device__ __forceinline__ u16 f2bf(float f){
  u32 r;
  asm("v_cvt_pk_bf16_f32 %0, %1, %1" : "=v"(r) : "v"(f));  // RNE, 1 instr
  return (u16)r;
}
__device__ __forceinline__ float bf2f(u16 h){ return __uint_as_float(((u32)h) << 16); }
__device__ __forceinline__ f32x4 splat4(float x){ f32x4 v = {x,x,x,x}; return v; }
__device__ __forceinline__ float sigm(float x){ return 1.f/(1.f + __expf(-x)); }
__device__ __forceinline__ float tanh_(float x){ float e = __expf(2.f*x); return 1.f - 2.f/(e + 1.f); }

#define MFMA16(a,b,c) __builtin_amdgcn_mfma_f32_16x16x32_bf16(a,b,c,0,0,0)
#define ATOM_ST(p,v) __hip_atomic_store((p),(v),__ATOMIC_RELAXED,__HIP_MEMORY_SCOPE_AGENT)
#define ATOM_LD(p)   __hip_atomic_load((p),__ATOMIC_RELAXED,__HIP_MEMORY_SCOPE_AGENT)
// merged 3-term hi/lo product (r5/r11-verified numerics; per-gate order unchanged)
#define DOT3(acc, XH, XL, WH, WL) \
  acc = MFMA16(XH, WH, acc); acc = MFMA16(XL, WH, acc); acc = MFMA16(XH, WL, acc);

__global__ void reset_flags(int* flags) {
  if (threadIdx.x < NWG) flags[threadIdx.x * 32] = -1;
}

// ---- per-step: gate-split pipelined schedule ----
// fragments+cur batched upfront; R-MFMAs -> sigm(R) || Z-MFMAs -> sigm(Z) || H,I-MFMAs -> tanh+wb
#define STEP(DD_) {                                                      \
  enum { DD = DD_, PS = (DD&1)*SBUF, PN = ((DD&1)^1)*SBUF,               \
         PU = (DD&1)*UBUF, PV = ((DD&1)^1)*UBUF };                       \
  float nv[4];                                                           \
  { int cc = 4*e + 2 + DD; if (cc > 511) cc = 511;                       \
    nv[0] = frow0[cc]; nv[1] = frow1[cc];                                \
    nv[2] = frow2[cc]; nv[3] = frow3[cc]; }                              \
  short8 Afh[6], Afl[6], Xfh[2], Xfl[2];                                 \
  _Pragma("unroll")                                                      \
  for (int kk = 0; kk < 6; ++kk) {                                       \
    const int _o = PS + aoff + (kk>>1)*PR + (kk&1)*32;                   \
    Afh[kk] = *(const short8*)&sh[_o];                                   \
    Afl[kk] = *(const short8*)&sl[_o];                                   \
  }                                                                      \
  _Pragma("unroll")                                                      \
  for (int kt = 0; kt < 2; ++kt) {                                       \
    const int _o = PU + aoff + kt*32;                                    \
    Xfh[kt] = *(const short8*)&uh[_o];                                   \
    Xfl[kt] = *(const short8*)&ul[_o];                                   \
  }                                                                      \
  float curv[4];                                                         \
  _Pragma("unroll")                                                      \
  for (int j = 0; j < 4; ++j) {                                          \
    const int m = kgrp*4 + j;                                            \
    curv[j] = bf2f(uh[PU + m*PR + ch]) + bf2f(ul[PU + m*PR + ch]);       \
  }                                                                      \
  f32x4 aR = splat4(biasR);                                              \
  _Pragma("unroll")                                                      \
  for (int kk = 0; kk < 6; ++kk) { DOT3(aR, Afh[kk], Afl[kk], BihH[0][kk], BihL[0][kk]) } \
  _Pragma("unroll")                                                      \
  for (int kt = 0; kt < 2; ++kt) { DOT3(aR, Xfh[kt], Xfl[kt], BhhH[0][kt], BhhL[0][kt]) } \
  float rr[4];                                                           \
  _Pragma("unroll")                                                      \
  for (int j = 0; j < 4; ++j) rr[j] = sigm(aR[j]);                       \
  f32x4 aZ = splat4(biasZ);                                              \
  _Pragma("unroll")                                                      \
  for (int kk = 0; kk < 6; ++kk) { DOT3(aZ, Afh[kk], Afl[kk], BihH[1][kk], BihL[1][kk]) } \
  _Pragma("unroll")                                                      \
  for (int kt = 0; kt < 2; ++kt) { DOT3(aZ, Xfh[kt], Xfl[kt], BhhH[1][kt], BhhL[1][kt]) } \
  float zz[4];                                                           \
  _Pragma("unroll")                                                      \
  for (int j = 0; j < 4; ++j) zz[j] = sigm(aZ[j]);                       \
  f32x4 aH = splat4(biasHn);                                             \
  _Pragma("unroll")                                                      \
  for (int kt = 0; kt < 2; ++kt) { DOT3(aH, Xfh[kt], Xfl[kt], BhhH[2][kt], BhhL[2][kt]) } \
  f32x4 aI = splat4(biasI);                                              \
  _Pragma("unroll")                                                      \
  for (int kk = 0; kk < 6; ++kk) { DOT3(aI, Afh[kk], Afl[kk], BihH[2][kk], BihL[2][kk]) } \
  _Pragma("unroll")                                                      \
  for (int j = 0; j < 4; ++j) {                                          \
    const int m = kgrp*4 + j;                                            \
    const int absr = a - 4 + m;                                          \
    float nn = tanh_(aI[j] + rr[j]*aH[j]);                               \
    float v = (1.f - zz[j])*nn + zz[j]*curv[j];                          \
    if ((unsigned)absr < 512u) {                                         \
      u16 h_ = f2bf(v);                                                  \
      sh[PN + (m+1)*PR + ch] = h_;                                       \
      sl[PN + (m+1)*PR + ch] = f2bf(v - bf2f(h_));                       \
      if (m >= 4 && m < 12) ost[(dc0 + DD)*512 + (m-4)*64 + ch] = h_;    \
    }                                                                    \
    if (DD == 3) {                                                       \
      if (kgrp == 1) ATOM_ST(&ws->haloT[g][e&1][j*64 + ch], __float_as_uint(v)); \
      if (kgrp == 2) ATOM_ST(&ws->haloB[g][e&1][j*64 + ch], __float_as_uint(v)); \
    }                                                                    \
  }                                                                      \
  _Pragma("unroll")                                                      \
  for (int i = 0; i < 4; ++i) {                                          \
    float v = nv[i];                                                     \
    u16 h_ = f2bf(v);                                                    \
    uh[PV + uoff[i]] = h_;                                               \
    ul[PV + uoff[i]] = f2bf(v - bf2f(h_));                               \
  }                                                                      \
}

__global__ __launch_bounds__(256, 1)
void gru_scan(const float* __restrict__ feat,
              const float* __restrict__ w_ih,
              const float* __restrict__ w_hh,
              const float* __restrict__ b_ih,
              const float* __restrict__ b_hh,
              float* __restrict__ out,
              Ws* __restrict__ ws)
{
  __shared__ __align__(16) u16 sh[2*SBUF], sl[2*SBUF];
  __shared__ __align__(16) u16 uh[2*UBUF], ul[2*UBUF];
  __shared__ __align__(16) u16 ost[16*512];   // [dc][row0..7][ch] bf16, conflict-free writes

  const int tid  = threadIdx.x;
  const int wgid = blockIdx.x;
  const int g    = (wgid & 7) * 32 + (wgid >> 3);   // XCD-local band chains (bijective)
  const int b    = g >> 6;
  const int kband= g & 63;
  const int a    = kband * 8;
  const int lane = tid & 63;
  const int wid  = tid >> 6;
  const int ln16 = lane & 15;
  const int kgrp = lane >> 4;
  const int ch   = wid*16 + ln16;

  // ---- weights (hi+lo) in registers: 192 VGPR ----
  short8 BihH[3][6], BihL[3][6], BhhH[3][2], BhhL[3][2];
#pragma unroll
  for (int gg = 0; gg < 3; ++gg) {
    const int n = gg*64 + ch;
#pragma unroll
    for (int kk = 0; kk < 6; ++kk) {
      short8 vh, vl;
#pragma unroll
      for (int j = 0; j < 8; ++j) {
        float wv = w_ih[n*192 + kk*32 + kgrp*8 + j];
        u16 h = f2bf(wv); vh[j] = (short)h; vl[j] = (short)f2bf(wv - bf2f(h));
      }
      BihH[gg][kk] = vh; BihL[gg][kk] = vl;
    }
#pragma unroll
    for (int kt = 0; kt < 2; ++kt) {
      short8 vh, vl;
#pragma unroll
      for (int j = 0; j < 8; ++j) {
        float wv = w_hh[n*64 + kt*32 + kgrp*8 + j];
        u16 h = f2bf(wv); vh[j] = (short)h; vl[j] = (short)f2bf(wv - bf2f(h));
      }
      BhhH[gg][kt] = vh; BhhL[gg][kt] = vl;
    }
  }
  const float biasR  = b_ih[ch]       + b_hh[ch];
  const float biasZ  = b_ih[64 + ch]  + b_hh[64 + ch];
  const float biasI  = b_ih[128 + ch];
  const float biasHn = b_hh[128 + ch];

  // ---- static per-thread offsets ----
  const int aoff = ln16*PR + kgrp*8;
  const int lch  = tid & 63;
  const int lr0  = wid * 4;                 // loader u-rows m=lr0..lr0+3
  int uoff[4];
#pragma unroll
  for (int i = 0; i < 4; ++i) uoff[i] = (lr0 + i)*PR + lch;

  const float* fbase = feat + (size_t)(b*C64 + lch)*HWp;
  // clamped row pointers (no masks: garbage flows only into discarded margin rows)
  const int ar0 = a - 4 + lr0;
  int r0 = ar0+0; r0 = r0 < 0 ? 0 : (r0 > 511 ? 511 : r0);
  int r1 = ar0+1; r1 = r1 < 0 ? 0 : (r1 > 511 ? 511 : r1);
  int r2 = ar0+2; r2 = r2 < 0 ? 0 : (r2 > 511 ? 511 : r2);
  int r3 = ar0+3; r3 = r3 < 0 ? 0 : (r3 > 511 ? 511 : r3);
  const float* frow0 = fbase + (size_t)r0*512;
  const float* frow1 = fbase + (size_t)r1*512;
  const float* frow2 = fbase + (size_t)r2*512;
  const float* frow3 = fbase + (size_t)r3*512;

  // ---- init ----
  for (int i = tid; i < 2*SBUF; i += 256) { sh[i] = 0; sl[i] = 0; }
  for (int i = tid; i < 2*UBUF; i += 256) { uh[i] = 0; ul[i] = 0; }
  __syncthreads();
  // feat col 0 -> state buf0 slots 0..17 + owned passthrough (slots 5..12)
#pragma unroll
  for (int i = 0; i < 5; ++i) {
    const int s = wid + 4*i;
    if (s < SLOTS) {
      const int absr = a - 5 + s;
      if ((unsigned)absr < 512u) {
        float v = fbase[(size_t)absr*512];
        u16 h_ = f2bf(v);
        sh[s*PR + lch] = h_;
        sl[s*PR + lch] = f2bf(v - bf2f(h_));
        if (s >= 5 && s <= 12) out[(size_t)(b*C64 + lch)*HWp + (size_t)absr*512] = v;
      }
    }
  }
  // u buf0 <- col 1 (clamped rows)
  {
    const float* fr[4] = { frow0, frow1, frow2, frow3 };
#pragma unroll
    for (int i = 0; i < 4; ++i) {
      float v1 = fr[i][1];
      u16 h_ = f2bf(v1);
      uh[uoff[i]] = h_;
      ul[uoff[i]] = f2bf(v1 - bf2f(h_));
    }
  }
  __syncthreads();

  // ---- epoch loop: 4 columns per epoch, static parity ----
#pragma unroll 1
  for (int e = 0; e < NEP; ++e) {
    const int dc0 = (e & 3) * 4;
    STEP(0)
    __syncthreads();
    STEP(1)
    __syncthreads();
    STEP(2)
    if (e < NEP-1) {
      __syncthreads();
      STEP(3)
    }

    // ---- boundary ----
    asm volatile("s_waitcnt vmcnt(0)" ::: "memory");   // per-wave drain (halo sends)
    __syncthreads();
    if (e < NEP-1 && tid == 0) ATOM_ST(&ws->flags[g][0], e);

    if (wid == 0 || wid == 3) {
      if ((e & 3) == 3) {      // flush 16 finished columns; 64B/lane-row, coalesced
        const int t128  = (wid == 0) ? lane : 64 + lane;
        const int wbase = 4*(e-3) + 1;
#pragma unroll
        for (int i = 0; i < 4; ++i) {
          const int pi  = t128 + 128*i;      // row*64 + ch
          const int row = pi >> 6, c = pi & 63;
          float* go = out + (size_t)(b*C64 + c)*HWp + (size_t)(a + row)*512 + wbase;
#pragma unroll
          for (int dc = 0; dc < 16; ++dc)
            if (wbase + dc <= 511) go[dc] = bf2f(ost[dc*512 + row*64 + c]);
        }
      }
    } else if (e < NEP-1) {
      if (wid == 1 && kband > 0) {       // top margin <- g-1's haloB (absr a-4..a-1)
        int f = -1, guard = 0;
        while (f < e && ++guard < (1<<17)) {
          if (lane == 0) f = ATOM_LD(&ws->flags[g-1][0]);
          f = __shfl(f, 0);
          if (f < e) __builtin_amdgcn_s_sleep(1);
        }
        asm volatile("" ::: "memory");
#pragma unroll
        for (int i = 0; i < 4; ++i) {    // absr a-4+i -> buf0 slot 1+i
          float v = __uint_as_float(ATOM_LD(&ws->haloB[g-1][e&1][i*64 + lane]));
          u16 h_ = f2bf(v);
          sh[(1+i)*PR + lane] = h_;
          sl[(1+i)*PR + lane] = f2bf(v - bf2f(h_));
        }
      }
      if (wid == 2 && kband < 63) {      // bottom margin <- g+1's haloT (absr a+8..a+11)
        int f = -1, guard = 0;
        while (f < e && ++guard < (1<<17)) {
          if (lane == 0) f = ATOM_LD(&ws->flags[g+1][0]);
          f = __shfl(f, 0);
          if (f < e) __builtin_amdgcn_s_sleep(1);
        }
        asm volatile("" ::: "memory");
#pragma unroll
        for (int i = 0; i < 4; ++i) {    // absr a+8+i -> buf0 slot 13+i
          float v = __uint_as_float(ATOM_LD(&ws->haloT[g+1][e&1][i*64 + lane]));
          u16 h_ = f2bf(v);
          sh[(13+i)*PR + lane] = h_;
          sl[(13+i)*PR + lane] = f2bf(v - bf2f(h_));
        }
      }
    }
    __syncthreads();   // margins in buf0 + flush done before next epoch
  }
}

extern "C" void kernel_launch(void* const* d_in, const int* in_sizes, int n_in,
                              void* d_out, int out_size, void* d_ws, size_t ws_size,
                              hipStream_t stream) {
  const float* feat = (const float*)d_in[0];
  const float* wih  = (const float*)d_in[1];
  const float* whh  = (const float*)d_in[2];
  const float* bih  = (const float*)d_in[3];
  const float* bhh  = (const float*)d_in[4];
  float* out = (float*)d_out;
  Ws* ws = (Ws*)d_ws;

  reset_flags<<<1, NWG, 0, stream>>>((int*)ws->flags);
  gru_scan<<<NWG, 256, 0, stream>>>(feat, wih, whh, bih, bhh, out, ws);
}